// Round 10
// baseline (152.831 us; speedup 1.0000x reference)
//
#include <hip/hip_runtime.h>
#include <hip/hip_bf16.h>

#define BATCH 16384
#define FIN   768
#define FOUT  512

#define BK 32
#define NT (FIN / BK)   // 24 K-iterations

typedef __attribute__((ext_vector_type(8))) short short8;
typedef __attribute__((ext_vector_type(4))) float floatx4;

// packed fp32x2 -> bf16x2, round-to-nearest-even (gfx940+ VOP3)
__device__ __forceinline__ unsigned int cvt_pk_bf16(float a, float b) {
    unsigned int r;
    asm("v_cvt_pk_bf16_f32 %0, %1, %2" : "=v"(r) : "v"(a), "v"(b));
    return r;
}

// async 16B global -> LDS DMA; HW scatters lane i to ldsbase + i*16
__device__ __forceinline__ void load_lds_16(const void* g, void* l) {
    __builtin_amdgcn_global_load_lds(
        (const __attribute__((address_space(1))) unsigned int*)g,
        (__attribute__((address_space(3))) unsigned int*)l,
        16, 0, 0);
}

// one-shot W1 fp32 -> bf16 (393216 elems, 8 per thread, 192 blocks)
__global__ __launch_bounds__(256) void cvt_w1(
    const float* __restrict__ W1, unsigned short* __restrict__ W1b)
{
    int base = (blockIdx.x * 256 + threadIdx.x) * 8;
    float4 a = *(const float4*)(W1 + base);
    float4 b = *(const float4*)(W1 + base + 4);
    uint4 o;
    o.x = cvt_pk_bf16(a.x, a.y); o.y = cvt_pk_bf16(a.z, a.w);
    o.z = cvt_pk_bf16(b.x, b.y); o.w = cvt_pk_bf16(b.z, b.w);
    *(uint4*)(W1b + base) = o;
}

// One block = one CU, 8 waves x (128m x 64n) wave tiles over 128 GEMM rows
// (64 batch rows x both perspectives) x all 512 features. Single barrier
// per K-iter (R9 pipeline). LDS slot-swizzles are conflict-free for both
// stores and b128 reads (distinct bank-quads per 8-lane phase):
//   A: slot = ((rig + 4*chunk)&15) + 16*chunk   (reg-store path)
//   B: slot = rig + 16*((chunk + rig)&3)        (DMA lane-order path)
// Fused epilogue: clip + W2-dot + LDS reduce + sigmoid -> out.
__global__ __launch_bounds__(512, 2) void pn_gemm(
    const float* __restrict__ stm, const float* __restrict__ nstm,
    const unsigned short* __restrict__ W1b, const float* __restrict__ b1,
    const float* __restrict__ W2, const float* __restrict__ b2,
    float* __restrict__ out)
{
    __shared__ __align__(16) unsigned short As[2][128 * 32];  // 2 x 8 KB
    __shared__ __align__(16) unsigned short Bs[2][512 * 32];  // 2 x 32 KB

    const int tid  = threadIdx.x;
    const int lane = tid & 63;
    const int wave = tid >> 6;    // 0..7; wave covers cols wave*64 .. +63
    const int quad = lane >> 4;
    const int l16  = lane & 15;

    const int b0 = blockIdx.x * 64;   // batch rows owned by this block

    // ---- A staging: thread t covers GEMM row t>>2, chunk t&3 (32 B fp32)
    const int arow = tid >> 2;        // 0..127
    const int ach  = tid & 3;
    const float* aSrc = ((arow < 64) ? stm  + (size_t)(b0 + arow) * FIN
                                     : nstm + (size_t)(b0 + arow - 64) * FIN) + ach * 8;
    const int aSlot = (((arow & 15) + 4 * ach) & 15) + 16 * ach;
    const int aOff  = (arow >> 4) * 512 + aSlot * 8;   // ushort index

    // ---- B staging: 4 DMA/wave; instr i -> group J = wave*4+i (rows 16J..+15)
    const int brig = lane & 15;                       // row within group
    const int bch  = ((lane >> 4) - brig) & 3;        // swizzled source chunk

    floatx4 acc[8][4];
    #pragma unroll
    for (int i = 0; i < 8; ++i)
        #pragma unroll
        for (int j = 0; j < 4; ++j)
            acc[i][j] = (floatx4)0.0f;

    // ---- prologue: stage tile 0
    float4 ap0 = *(const float4*)(aSrc);
    float4 ap1 = *(const float4*)(aSrc + 4);
    #pragma unroll
    for (int i = 0; i < 4; ++i) {
        const int J = wave * 4 + i;
        load_lds_16(W1b + (size_t)(J * 16 + brig) * FIN + bch * 8,
                    &Bs[0][J * 512]);
    }

    for (int t = 0; t < NT; ++t) {
        const int cur = t & 1;
        const int nxt = cur ^ 1;

        // publish A(t) (regs loaded last iter)
        {
            uint4 o;
            o.x = cvt_pk_bf16(ap0.x, ap0.y); o.y = cvt_pk_bf16(ap0.z, ap0.w);
            o.z = cvt_pk_bf16(ap1.x, ap1.y); o.w = cvt_pk_bf16(ap1.z, ap1.w);
            *(uint4*)(&As[cur][aOff]) = o;
        }
        __syncthreads();   // drains B-DMA(t) + A-store(t); tile t fully published

        // issue staging for t+1 — lands during tile t's compute
        if (t + 1 < NT) {
            const int kn = (t + 1) * BK;
            #pragma unroll
            for (int i = 0; i < 4; ++i) {
                const int J = wave * 4 + i;
                load_lds_16(W1b + (size_t)(J * 16 + brig) * FIN + kn + bch * 8,
                            &Bs[nxt][J * 512]);
            }
            ap0 = *(const float4*)(aSrc + kn);
            ap1 = *(const float4*)(aSrc + kn + 4);
        }

        // compute tile t: 8 A-frags (all 128 rows) x 4 B-frags (64 cols)
        short8 af[8], bfr[4];
        #pragma unroll
        for (int mi = 0; mi < 8; ++mi) {
            const int slot = ((l16 + 4 * quad) & 15) + 16 * quad;
            af[mi] = *(const short8*)(&As[cur][mi * 512 + slot * 8]);
        }
        #pragma unroll
        for (int ni = 0; ni < 4; ++ni) {
            const int G = wave * 4 + ni;
            const int slot = l16 + 16 * ((quad + l16) & 3);
            bfr[ni] = *(const short8*)(&Bs[cur][G * 512 + slot * 8]);
        }
        #pragma unroll
        for (int mi = 0; mi < 8; ++mi)
            #pragma unroll
            for (int ni = 0; ni < 4; ++ni)
                acc[mi][ni] = __builtin_amdgcn_mfma_f32_16x16x32_bf16(
                    af[mi], bfr[ni], acc[mi][ni], 0, 0, 0);
    }

    // ---- fused epilogue. C/D layout: col = lane&15, row = quad*4 + reg.
    float b1v[4], w2v0[4], w2v1[4];
    #pragma unroll
    for (int ni = 0; ni < 4; ++ni) {
        int col = wave * 64 + ni * 16 + l16;
        b1v[ni]  = b1[col];
        w2v0[ni] = W2[col];          // stm half  (GEMM rows 0..63)
        w2v1[ni] = W2[FOUT + col];   // nstm half (GEMM rows 64..127)
    }

    __syncthreads();                 // all MFMA LDS reads done; reuse As
    float* Epi = (float*)As;         // [128 rows][8 waves] partials (4 KB)

    #pragma unroll
    for (int mi = 0; mi < 8; ++mi) {
        const float* w2v = (mi < 4) ? w2v0 : w2v1;
        #pragma unroll
        for (int r = 0; r < 4; ++r) {
            float s = 0.0f;
            #pragma unroll
            for (int ni = 0; ni < 4; ++ni) {
                float h = acc[mi][ni][r] + b1v[ni];
                h = fminf(fmaxf(h, 0.0f), 1.0f);
                s += h * w2v[ni];
            }
            s += __shfl_xor(s, 1);
            s += __shfl_xor(s, 2);
            s += __shfl_xor(s, 4);
            s += __shfl_xor(s, 8);
            if (l16 == 0) {
                Epi[(mi * 16 + quad * 4 + r) * 8 + wave] = s;
            }
        }
    }
    __syncthreads();

    if (tid < 64) {
        float x = b2[0];
        #pragma unroll
        for (int j = 0; j < 8; ++j)
            x += Epi[tid * 8 + j] + Epi[(tid + 64) * 8 + j];
        out[b0 + tid] = 1.0f / (1.0f + expf(-x));
    }
}

extern "C" void kernel_launch(void* const* d_in, const int* in_sizes, int n_in,
                              void* d_out, int out_size, void* d_ws, size_t ws_size,
                              hipStream_t stream)
{
    (void)in_sizes; (void)n_in; (void)out_size; (void)ws_size;
    const float* stm  = (const float*)d_in[0];
    const float* nstm = (const float*)d_in[1];
    const float* W1   = (const float*)d_in[2];
    const float* b1   = (const float*)d_in[3];
    const float* W2   = (const float*)d_in[4];
    const float* b2   = (const float*)d_in[5];
    float* out = (float*)d_out;
    unsigned short* W1b = (unsigned short*)d_ws;   // bf16 W1 copy (768 KB)

    cvt_w1<<<dim3((FOUT * FIN) / (256 * 8)), dim3(256), 0, stream>>>(W1, W1b);
    pn_gemm<<<dim3(BATCH / 64), dim3(512), 0, stream>>>(
        stm, nstm, W1b, b1, W2, b2, out);
}